// Round 1
// baseline (300.743 us; speedup 1.0000x reference)
//
#include <hip/hip_runtime.h>
#include <math.h>

#define B_ 8
#define N_ 2048
#define D_ 512
#define NROWS (B_ * N_)  // 16384
#define NEG_ALPHA 0.1f

typedef __bf16 bf16;
typedef __bf16 bf16x4 __attribute__((ext_vector_type(4)));
typedef __bf16 bf16x8 __attribute__((ext_vector_type(8)));
typedef float f32x4 __attribute__((ext_vector_type(4)));
typedef float f32x16 __attribute__((ext_vector_type(16)));

// ---------------------------------------------------------------------------
// k_prep: Wt[dout][din] = bf16(W[din][dout])
// ---------------------------------------------------------------------------
__global__ __launch_bounds__(256) void k_prep(const float* __restrict__ W,
                                              bf16* __restrict__ Wt) {
  const int dout = blockIdx.x;
  const int t = threadIdx.x;
#pragma unroll
  for (int p = 0; p < 2; ++p) {
    int din = t + p * 256;
    Wt[dout * D_ + din] = (bf16)W[din * D_ + dout];
  }
}

// ---------------------------------------------------------------------------
// k_wa: wa1 = W @ a1, wa2 = W @ a2 (fp32-exact logits path)
// ---------------------------------------------------------------------------
__global__ __launch_bounds__(256) void k_wa(const float* __restrict__ W,
                                            const float* __restrict__ a1,
                                            const float* __restrict__ a2,
                                            float* __restrict__ wa1,
                                            float* __restrict__ wa2) {
  const int wv = threadIdx.x >> 6, lane = threadIdx.x & 63;
  const int row = blockIdx.x * 4 + wv;
  const float* wr = W + (size_t)row * D_;
  float d1 = 0.f, d2 = 0.f;
#pragma unroll
  for (int p = 0; p < 8; ++p) {
    int c = lane + p * 64;
    float w = wr[c];
    d1 = fmaf(w, a1[c], d1);
    d2 = fmaf(w, a2[c], d2);
  }
#pragma unroll
  for (int off = 32; off > 0; off >>= 1) {
    d1 += __shfl_down(d1, off, 64);
    d2 += __shfl_down(d2, off, 64);
  }
  if (lane == 0) {
    wa1[row] = d1;
    wa2[row] = d2;
  }
}

// ---------------------------------------------------------------------------
// k_scores_x: s1[r] = X[r,:].wa1 ; s2[r] = X[r,:].wa2 (fp32, coalesced)
// ---------------------------------------------------------------------------
__global__ __launch_bounds__(256) void k_scores_x(const float* __restrict__ X,
                                                  const float* __restrict__ wa1,
                                                  const float* __restrict__ wa2,
                                                  float* __restrict__ s1,
                                                  float* __restrict__ s2) {
  const int wv = threadIdx.x >> 6, lane = threadIdx.x & 63;
  const int r = blockIdx.x * 4 + wv;
  const float* x = X + (size_t)r * D_;
  float d1 = 0.f, d2 = 0.f;
#pragma unroll
  for (int p = 0; p < 2; ++p) {
    int c = lane * 4 + p * 256;
    float4 xv = *(const float4*)&x[c];
    float4 w1 = *(const float4*)&wa1[c];
    float4 w2 = *(const float4*)&wa2[c];
    d1 += xv.x * w1.x + xv.y * w1.y + xv.z * w1.z + xv.w * w1.w;
    d2 += xv.x * w2.x + xv.y * w2.y + xv.z * w2.z + xv.w * w2.w;
  }
#pragma unroll
  for (int off = 32; off > 0; off >>= 1) {
    d1 += __shfl_down(d1, off, 64);
    d2 += __shfl_down(d2, off, 64);
  }
  if (lane == 0) {
    s1[r] = d1;
    s2[r] = d2;
  }
}

// ---------------------------------------------------------------------------
// k_hiddenT: Ht[dout][row] = bf16(sum_din Wt[dout][din] * X[row][din])
// BM=BN=128, BK=32, 256 thr, 16x16x32 MFMA + depth-1 register prefetch.
// ---------------------------------------------------------------------------
#define LDH 40

__global__ __launch_bounds__(256, 2) void k_hiddenT(const float* __restrict__ X,
                                                    const bf16* __restrict__ Wt,
                                                    bf16* __restrict__ Ht) {
  __shared__ bf16 As[128][LDH];
  __shared__ bf16 Bs[128][LDH];
  const int t = threadIdx.x;
  const int m0 = blockIdx.y * 128;
  const int n0 = blockIdx.x * 128;
  const int lane = t & 63, w = t >> 6;
  const int wm = w >> 1, wn = w & 1;
  const int l15 = lane & 15, q = lane >> 4;

  f32x4 acc[4][4];
#pragma unroll
  for (int i = 0; i < 4; ++i)
#pragma unroll
    for (int j = 0; j < 4; ++j) acc[i][j] = (f32x4){0.f, 0.f, 0.f, 0.f};

  bf16x8 av[2];
  float4 bv[4];
  // prologue loads (k0 = 0)
#pragma unroll
  for (int p = 0; p < 2; ++p) {
    int s = t + p * 256;
    av[p] = *(const bf16x8*)&Wt[(size_t)(m0 + (s >> 2)) * D_ + (s & 3) * 8];
  }
#pragma unroll
  for (int p = 0; p < 4; ++p) {
    int s = t + p * 256;
    bv[p] = *(const float4*)&X[(size_t)(n0 + (s >> 3)) * D_ + (s & 7) * 4];
  }

  for (int k0 = 0; k0 < D_; k0 += 32) {
    __syncthreads();  // previous iteration's readers done
#pragma unroll
    for (int p = 0; p < 2; ++p) {
      int s = t + p * 256;
      *(bf16x8*)&As[s >> 2][(s & 3) * 8] = av[p];
    }
#pragma unroll
    for (int p = 0; p < 4; ++p) {
      int s = t + p * 256;
      float4 v = bv[p];
      bf16x4 h = {(bf16)v.x, (bf16)v.y, (bf16)v.z, (bf16)v.w};
      *(bf16x4*)&Bs[s >> 3][(s & 7) * 4] = h;
    }
    __syncthreads();
    // prefetch next chunk
    if (k0 + 32 < D_) {
#pragma unroll
      for (int p = 0; p < 2; ++p) {
        int s = t + p * 256;
        av[p] = *(const bf16x8*)&Wt[(size_t)(m0 + (s >> 2)) * D_ + k0 + 32 + (s & 3) * 8];
      }
#pragma unroll
      for (int p = 0; p < 4; ++p) {
        int s = t + p * 256;
        bv[p] = *(const float4*)&X[(size_t)(n0 + (s >> 3)) * D_ + k0 + 32 + (s & 7) * 4];
      }
    }
    bf16x8 a[4], bb[4];
#pragma unroll
    for (int i = 0; i < 4; ++i)
      a[i] = *(const bf16x8*)&As[wm * 64 + i * 16 + l15][q * 8];
#pragma unroll
    for (int j = 0; j < 4; ++j)
      bb[j] = *(const bf16x8*)&Bs[wn * 64 + j * 16 + l15][q * 8];
#pragma unroll
    for (int i = 0; i < 4; ++i)
#pragma unroll
      for (int j = 0; j < 4; ++j)
        acc[i][j] =
            __builtin_amdgcn_mfma_f32_16x16x32_bf16(a[i], bb[j], acc[i][j], 0, 0, 0);
  }
#pragma unroll
  for (int i = 0; i < 4; ++i)
#pragma unroll
    for (int r = 0; r < 4; ++r) {
      int dout = m0 + wm * 64 + i * 16 + q * 4 + r;
#pragma unroll
      for (int j = 0; j < 4; ++j) {
        int row = n0 + wn * 64 + j * 16 + l15;
        Ht[(size_t)dout * NROWS + row] = (bf16)acc[i][j][r];
      }
    }
}

// ---------------------------------------------------------------------------
// k_attn: out = elu( softmax_row(mask(leaky(s1_i+s2_j))) @ H )
// 64 rows x 512 d per block, K=2048 in BK=64 chunks. 512 thr / 8 waves.
// 32x32x16 MFMA, wave-tile 64x64 (2x2 tiles).
// v2: no Hs staging — B-fragments read DIRECTLY from Ht (L2-resident,
//     2 MB/batch). Ps double-buffered -> ONE barrier per iteration.
//     XCD-affine flat grid: b = bid&7 so each batch's Ht slab lives in
//     its own XCD's 4 MiB L2. Graph (HBM, compulsory 134 MB) prefetched
//     depth-1 at top of body.
// ---------------------------------------------------------------------------
#define AT_BM 64
#define AT_BK 64
#define LDP 72

__global__ __launch_bounds__(512) void k_attn(const bf16* __restrict__ Ht,
                                              const int* __restrict__ graph,
                                              const float* __restrict__ s1,
                                              const float* __restrict__ s2,
                                              float* __restrict__ out) {
  __shared__ __align__(16) bf16 Ps[2][AT_BM][LDP];  // 18,432 B (double buf)
  __shared__ float s2s[N_];                         // 8 KB
  __shared__ float sum_part[AT_BM][8];              // 2 KB
  __shared__ float row_sum[AT_BM];

  const int t = threadIdx.x;
  const int bid = blockIdx.x;
  const int b = bid & 7;             // XCD-affine: batch b -> XCD b
  const int i0 = (bid >> 3) * AT_BM;
  const int lane = t & 63, w = t >> 6;
  const int r31 = lane & 31, half = lane >> 5;

  const bf16* Htb = Ht + (size_t)b * N_;
  const int* Gb = graph + ((size_t)b * N_ + i0) * N_;

  for (int c = t; c < N_; c += 512) s2s[c] = s2[b * N_ + c];

  const int pi = t >> 3;       // P row 0..63
  const int pj = (t & 7) * 8;  // P j-offset (8 values/thread)
  const float s1r = s1[b * N_ + i0 + pi];
  float rsum = 0.f;

  f32x16 acc[2][2];
#pragma unroll
  for (int i = 0; i < 2; ++i)
#pragma unroll
    for (int j = 0; j < 2; ++j)
#pragma unroll
      for (int r = 0; r < 16; ++r) acc[i][j][r] = 0.f;

  // prologue: graph prefetch for iter 0
  int4 g0 = *(const int4*)&Gb[(size_t)pi * N_ + pj];
  int4 g1 = *(const int4*)&Gb[(size_t)pi * N_ + pj + 4];

  __syncthreads();  // s2s ready

#pragma unroll 1
  for (int it = 0; it < N_ / AT_BK; ++it) {
    const int j0 = it * AT_BK;
    // issue next graph loads first (HBM ~900 cyc; consumed next iteration)
    int jn = j0 + AT_BK;
    if (jn >= N_) jn = 0;  // clamped dummy on last iter (uniform, L2-hit)
    int4 n0_ = *(const int4*)&Gb[(size_t)pi * N_ + jn + pj];
    int4 n1_ = *(const int4*)&Gb[(size_t)pi * N_ + jn + pj + 4];

    // compute P from this iteration's (prefetched) graph regs
    float pv[8];
    {
      int gg[8] = {g0.x, g0.y, g0.z, g0.w, g1.x, g1.y, g1.z, g1.w};
      f32x4 sA = *(const f32x4*)&s2s[j0 + pj];
      f32x4 sB = *(const f32x4*)&s2s[j0 + pj + 4];
      float sv[8] = {sA.x, sA.y, sA.z, sA.w, sB.x, sB.y, sB.z, sB.w};
#pragma unroll
      for (int q = 0; q < 8; ++q) {
        float e = s1r + sv[q];
        e = (e > 0.f) ? e : NEG_ALPHA * e;
        pv[q] = (gg[q] != 0) ? __expf(e) : 0.f;
        rsum += pv[q];
      }
    }
    const int cur = it & 1;
    {
      bf16x8 pb = {(bf16)pv[0], (bf16)pv[1], (bf16)pv[2], (bf16)pv[3],
                   (bf16)pv[4], (bf16)pv[5], (bf16)pv[6], (bf16)pv[7]};
      *(bf16x8*)&Ps[cur][pi][pj] = pb;
    }
    __syncthreads();  // Ps[cur] visible; prev-iter readers of other buf done

    // MFMA phase: A from LDS, B DIRECT from Ht (L2). One 128B line per
    // row per iteration, fully consumed by the 4 k-steps.
    const bf16* Hw0 = Htb + (size_t)(w * 64 + r31) * NROWS + j0;
    const bf16* Hw1 = Htb + (size_t)(w * 64 + 32 + r31) * NROWS + j0;
#pragma unroll
    for (int ks = 0; ks < 4; ++ks) {
      const int ko = ks * 16 + half * 8;
      bf16x8 a0 = *(const bf16x8*)&Ps[cur][r31][ko];
      bf16x8 a1 = *(const bf16x8*)&Ps[cur][32 + r31][ko];
      bf16x8 b0 = *(const bf16x8*)&Hw0[ko];
      bf16x8 b1 = *(const bf16x8*)&Hw1[ko];
      acc[0][0] = __builtin_amdgcn_mfma_f32_32x32x16_bf16(a0, b0, acc[0][0], 0, 0, 0);
      acc[0][1] = __builtin_amdgcn_mfma_f32_32x32x16_bf16(a0, b1, acc[0][1], 0, 0, 0);
      acc[1][0] = __builtin_amdgcn_mfma_f32_32x32x16_bf16(a1, b0, acc[1][0], 0, 0, 0);
      acc[1][1] = __builtin_amdgcn_mfma_f32_32x32x16_bf16(a1, b1, acc[1][1], 0, 0, 0);
    }
    g0 = n0_;
    g1 = n1_;
  }

  // row sums
  sum_part[pi][t & 7] = rsum;
  __syncthreads();
  if (t < AT_BM) {
    float s = 0.f;
#pragma unroll
    for (int k = 0; k < 8; ++k) s += sum_part[t][k];
    row_sum[t] = s;
  }
  __syncthreads();

  // epilogue: normalize + elu + store
  // C/D layout (32x32): col = lane&31, row = (r&3) + 8*(r>>2) + 4*half
#pragma unroll
  for (int mt = 0; mt < 2; ++mt) {
    float inv[16];
#pragma unroll
    for (int r = 0; r < 16; ++r)
      inv[r] = 1.f / row_sum[mt * 32 + (r & 3) + 8 * (r >> 2) + 4 * half];
#pragma unroll
    for (int nt = 0; nt < 2; ++nt) {
      const int d = w * 64 + nt * 32 + r31;
#pragma unroll
      for (int r = 0; r < 16; ++r) {
        int i = mt * 32 + (r & 3) + 8 * (r >> 2) + 4 * half;
        float x = acc[mt][nt][r] * inv[r];
        out[((size_t)b * N_ + i0 + i) * D_ + d] = (x > 0.f) ? x : expm1f(x);
      }
    }
  }
}

// ---------------------------------------------------------------------------
extern "C" void kernel_launch(void* const* d_in, const int* in_sizes, int n_in,
                              void* d_out, int out_size, void* d_ws,
                              size_t ws_size, hipStream_t stream) {
  const float* X = (const float*)d_in[0];
  const int* graph = (const int*)d_in[1];
  const float* W = (const float*)d_in[2];
  const float* a1 = (const float*)d_in[3];
  const float* a2 = (const float*)d_in[4];
  float* out = (float*)d_out;

  char* ws = (char*)d_ws;
  bf16* Wt = (bf16*)ws;                               // 512 KB
  bf16* Ht = (bf16*)(ws + (1 << 19));                 // 16 MB
  float* s1 = (float*)(ws + (1 << 19) + (16 << 20));
  float* s2 = s1 + NROWS;
  float* wa1 = s2 + NROWS;
  float* wa2 = wa1 + D_;

  hipLaunchKernelGGL(k_prep, dim3(512), dim3(256), 0, stream, W, Wt);
  hipLaunchKernelGGL(k_wa, dim3(128), dim3(256), 0, stream, W, a1, a2, wa1, wa2);
  hipLaunchKernelGGL(k_scores_x, dim3(NROWS / 4), dim3(256), 0, stream, X, wa1,
                     wa2, s1, s2);
  hipLaunchKernelGGL(k_hiddenT, dim3(NROWS / 128, D_ / 128), dim3(256), 0,
                     stream, X, Wt, Ht);
  hipLaunchKernelGGL(k_attn, dim3(N_ / AT_BM * B_), dim3(512), 0, stream, Ht,
                     graph, s1, s2, out);
}

// Round 2
// 276.565 us; speedup vs baseline: 1.0874x; 1.0874x over previous
//
#include <hip/hip_runtime.h>
#include <math.h>

#define B_ 8
#define N_ 2048
#define D_ 512
#define NROWS (B_ * N_)  // 16384
#define NEG_ALPHA 0.1f

typedef __bf16 bf16;
typedef __bf16 bf16x4 __attribute__((ext_vector_type(4)));
typedef __bf16 bf16x8 __attribute__((ext_vector_type(8)));
typedef float f32x4 __attribute__((ext_vector_type(4)));
typedef float f32x16 __attribute__((ext_vector_type(16)));

// HtB layout: per batch b (2 MB): chunk c = (d>>5)*(N_/16) + (j>>4), each
// chunk = 64 lanes x 8 bf16 (1 KB), element (l,e) <-> d = (d>>5)*32 + (l&31),
// j = (j>>4)*16 + (l>>5)*8 + e.  This is EXACTLY the mfma_32x32x16 B-fragment
// order, so k_attn's B-loads are single fully-coalesced 16B/lane loads.
#define HTB_BATCH ((D_ / 32) * (N_ / 16) * 512)  // 1,048,576 bf16 = 2 MB

// ---------------------------------------------------------------------------
// k_prep: Wt[dout][din] = bf16(W[din][dout])
// ---------------------------------------------------------------------------
__global__ __launch_bounds__(256) void k_prep(const float* __restrict__ W,
                                              bf16* __restrict__ Wt) {
  const int dout = blockIdx.x;
  const int t = threadIdx.x;
#pragma unroll
  for (int p = 0; p < 2; ++p) {
    int din = t + p * 256;
    Wt[dout * D_ + din] = (bf16)W[din * D_ + dout];
  }
}

// ---------------------------------------------------------------------------
// k_wa: wa1 = W @ a1, wa2 = W @ a2 (fp32-exact logits path)
// ---------------------------------------------------------------------------
__global__ __launch_bounds__(256) void k_wa(const float* __restrict__ W,
                                            const float* __restrict__ a1,
                                            const float* __restrict__ a2,
                                            float* __restrict__ wa1,
                                            float* __restrict__ wa2) {
  const int wv = threadIdx.x >> 6, lane = threadIdx.x & 63;
  const int row = blockIdx.x * 4 + wv;
  const float* wr = W + (size_t)row * D_;
  float d1 = 0.f, d2 = 0.f;
#pragma unroll
  for (int p = 0; p < 8; ++p) {
    int c = lane + p * 64;
    float w = wr[c];
    d1 = fmaf(w, a1[c], d1);
    d2 = fmaf(w, a2[c], d2);
  }
#pragma unroll
  for (int off = 32; off > 0; off >>= 1) {
    d1 += __shfl_down(d1, off, 64);
    d2 += __shfl_down(d2, off, 64);
  }
  if (lane == 0) {
    wa1[row] = d1;
    wa2[row] = d2;
  }
}

// ---------------------------------------------------------------------------
// k_scores_x: s1[r] = X[r,:].wa1 ; s2[r] = X[r,:].wa2 (fp32, coalesced)
// ---------------------------------------------------------------------------
__global__ __launch_bounds__(256) void k_scores_x(const float* __restrict__ X,
                                                  const float* __restrict__ wa1,
                                                  const float* __restrict__ wa2,
                                                  float* __restrict__ s1,
                                                  float* __restrict__ s2) {
  const int wv = threadIdx.x >> 6, lane = threadIdx.x & 63;
  const int r = blockIdx.x * 4 + wv;
  const float* x = X + (size_t)r * D_;
  float d1 = 0.f, d2 = 0.f;
#pragma unroll
  for (int p = 0; p < 2; ++p) {
    int c = lane * 4 + p * 256;
    float4 xv = *(const float4*)&x[c];
    float4 w1 = *(const float4*)&wa1[c];
    float4 w2 = *(const float4*)&wa2[c];
    d1 += xv.x * w1.x + xv.y * w1.y + xv.z * w1.z + xv.w * w1.w;
    d2 += xv.x * w2.x + xv.y * w2.y + xv.z * w2.z + xv.w * w2.w;
  }
#pragma unroll
  for (int off = 32; off > 0; off >>= 1) {
    d1 += __shfl_down(d1, off, 64);
    d2 += __shfl_down(d2, off, 64);
  }
  if (lane == 0) {
    s1[r] = d1;
    s2[r] = d2;
  }
}

// ---------------------------------------------------------------------------
// k_hiddenT: HtB[frag-layout] = bf16(sum_din Wt[dout][din] * X[row][din])
// BM=BN=128, BK=32, 256 thr, 16x16x32 MFMA + depth-1 register prefetch.
// Epilogue writes the MFMA-B-fragment-tiled HtB layout (see above).
// ---------------------------------------------------------------------------
#define LDH 40

__global__ __launch_bounds__(256, 2) void k_hiddenT(const float* __restrict__ X,
                                                    const bf16* __restrict__ Wt,
                                                    bf16* __restrict__ HtB) {
  __shared__ bf16 As[128][LDH];
  __shared__ bf16 Bs[128][LDH];
  const int t = threadIdx.x;
  const int m0 = blockIdx.y * 128;
  const int n0 = blockIdx.x * 128;
  const int lane = t & 63, w = t >> 6;
  const int wm = w >> 1, wn = w & 1;
  const int l15 = lane & 15, q = lane >> 4;

  f32x4 acc[4][4];
#pragma unroll
  for (int i = 0; i < 4; ++i)
#pragma unroll
    for (int j = 0; j < 4; ++j) acc[i][j] = (f32x4){0.f, 0.f, 0.f, 0.f};

  bf16x8 av[2];
  float4 bv[4];
  // prologue loads (k0 = 0)
#pragma unroll
  for (int p = 0; p < 2; ++p) {
    int s = t + p * 256;
    av[p] = *(const bf16x8*)&Wt[(size_t)(m0 + (s >> 2)) * D_ + (s & 3) * 8];
  }
#pragma unroll
  for (int p = 0; p < 4; ++p) {
    int s = t + p * 256;
    bv[p] = *(const float4*)&X[(size_t)(n0 + (s >> 3)) * D_ + (s & 7) * 4];
  }

  for (int k0 = 0; k0 < D_; k0 += 32) {
    __syncthreads();  // previous iteration's readers done
#pragma unroll
    for (int p = 0; p < 2; ++p) {
      int s = t + p * 256;
      *(bf16x8*)&As[s >> 2][(s & 3) * 8] = av[p];
    }
#pragma unroll
    for (int p = 0; p < 4; ++p) {
      int s = t + p * 256;
      float4 v = bv[p];
      bf16x4 h = {(bf16)v.x, (bf16)v.y, (bf16)v.z, (bf16)v.w};
      *(bf16x4*)&Bs[s >> 3][(s & 7) * 4] = h;
    }
    __syncthreads();
    // prefetch next chunk
    if (k0 + 32 < D_) {
#pragma unroll
      for (int p = 0; p < 2; ++p) {
        int s = t + p * 256;
        av[p] = *(const bf16x8*)&Wt[(size_t)(m0 + (s >> 2)) * D_ + k0 + 32 + (s & 3) * 8];
      }
#pragma unroll
      for (int p = 0; p < 4; ++p) {
        int s = t + p * 256;
        bv[p] = *(const float4*)&X[(size_t)(n0 + (s >> 3)) * D_ + k0 + 32 + (s & 7) * 4];
      }
    }
    bf16x8 a[4], bb[4];
#pragma unroll
    for (int i = 0; i < 4; ++i)
      a[i] = *(const bf16x8*)&As[wm * 64 + i * 16 + l15][q * 8];
#pragma unroll
    for (int j = 0; j < 4; ++j)
      bb[j] = *(const bf16x8*)&Bs[wn * 64 + j * 16 + l15][q * 8];
#pragma unroll
    for (int i = 0; i < 4; ++i)
#pragma unroll
      for (int j = 0; j < 4; ++j)
        acc[i][j] =
            __builtin_amdgcn_mfma_f32_16x16x32_bf16(a[i], bb[j], acc[i][j], 0, 0, 0);
  }
#pragma unroll
  for (int i = 0; i < 4; ++i)
#pragma unroll
    for (int r = 0; r < 4; ++r) {
      int dout = m0 + wm * 64 + i * 16 + q * 4 + r;
#pragma unroll
      for (int j = 0; j < 4; ++j) {
        int row = n0 + wn * 64 + j * 16 + l15;
        int bb_ = row >> 11;          // batch
        int jj = row & (N_ - 1);      // j within batch
        size_t addr = (size_t)bb_ * HTB_BATCH +
                      ((size_t)((dout >> 5) * (N_ / 16) + (jj >> 4)) * 64 +
                       ((jj >> 3) & 1) * 32 + (dout & 31)) *
                          8 +
                      (jj & 7);
        HtB[addr] = (bf16)acc[i][j][r];
      }
    }
}

// ---------------------------------------------------------------------------
// k_attn: out = elu( softmax_row(mask(leaky(s1_i+s2_j))) @ H )
// 64 rows x 512 d per block, K=2048 in BK=64 chunks. 512 thr / 8 waves.
// v3: B-fragments loaded from the frag-tiled HtB layout -> every B load is a
//     single fully-coalesced 16B/lane global load (1 KB/instr) from the
//     L2-resident 2 MB/batch slab. Depth-1 B register prefetch + depth-2
//     graph prefetch, static register indexing via 2x-unrolled loop body.
//     One barrier/iter (Ps double-buffered). XCD-affine: b = bid&7.
// ---------------------------------------------------------------------------
#define AT_BM 64
#define AT_BK 64
#define LDP 72
#define NIT (N_ / AT_BK)  // 32

#define ATTN_BODY(PS, BC, BN, G0, G1, IT)                                      \
  {                                                                            \
    const int j0_ = (IT)*AT_BK;                                                \
    int gg[8] = {G0.x, G0.y, G0.z, G0.w, G1.x, G1.y, G1.z, G1.w};              \
    { /* issue graph loads for IT+2 (HBM ~900cy, 2 iters of cover) */          \
      int itn = (IT) + 2;                                                      \
      int jg = (itn < NIT) ? itn * AT_BK : 0;                                  \
      G0 = *(const int4*)&Gb[(size_t)pi * N_ + jg + pj];                       \
      G1 = *(const int4*)&Gb[(size_t)pi * N_ + jg + pj + 4];                   \
    }                                                                          \
    float pv[8];                                                               \
    {                                                                          \
      f32x4 sA = *(const f32x4*)&s2s[j0_ + pj];                                \
      f32x4 sB = *(const f32x4*)&s2s[j0_ + pj + 4];                            \
      float sv[8] = {sA.x, sA.y, sA.z, sA.w, sB.x, sB.y, sB.z, sB.w};          \
      _Pragma("unroll") for (int q_ = 0; q_ < 8; ++q_) {                       \
        float e = s1r + sv[q_];                                                \
        e = (e > 0.f) ? e : NEG_ALPHA * e;                                     \
        pv[q_] = (gg[q_] != 0) ? __expf(e) : 0.f;                              \
        rsum += pv[q_];                                                        \
      }                                                                        \
    }                                                                          \
    {                                                                          \
      bf16x8 pb = {(bf16)pv[0], (bf16)pv[1], (bf16)pv[2], (bf16)pv[3],         \
                   (bf16)pv[4], (bf16)pv[5], (bf16)pv[6], (bf16)pv[7]};        \
      *(bf16x8*)&Ps[PS][pi][pj] = pb;                                          \
    }                                                                          \
    __syncthreads(); /* Ps[PS] visible; other-buffer readers done */           \
    { /* depth-1 B prefetch for IT+1 (coalesced 1KB loads, L2) */              \
      int j0n = ((IT) + 1 < NIT) ? ((IT) + 1) * AT_BK : 0;                     \
      _Pragma("unroll") for (int nt = 0; nt < 2; ++nt)                         \
          _Pragma("unroll") for (int ks = 0; ks < 4; ++ks)                     \
              BN[nt][ks] = *(const bf16x8*)&Hb[(size_t)((                      \
                  ((w * 2 + nt) * (N_ / 16) + (j0n >> 4) + ks) * 64 + lane))   \
                  * 8];                                                        \
    }                                                                          \
    _Pragma("unroll") for (int ks = 0; ks < 4; ++ks) {                         \
      const int ko = ks * 16 + hf * 8;                                         \
      bf16x8 a0 = *(const bf16x8*)&Ps[PS][r31][ko];                            \
      bf16x8 a1 = *(const bf16x8*)&Ps[PS][32 + r31][ko];                       \
      acc[0][0] = __builtin_amdgcn_mfma_f32_32x32x16_bf16(a0, BC[0][ks],       \
                                                          acc[0][0], 0, 0, 0); \
      acc[0][1] = __builtin_amdgcn_mfma_f32_32x32x16_bf16(a0, BC[1][ks],       \
                                                          acc[0][1], 0, 0, 0); \
      acc[1][0] = __builtin_amdgcn_mfma_f32_32x32x16_bf16(a1, BC[0][ks],       \
                                                          acc[1][0], 0, 0, 0); \
      acc[1][1] = __builtin_amdgcn_mfma_f32_32x32x16_bf16(a1, BC[1][ks],       \
                                                          acc[1][1], 0, 0, 0); \
    }                                                                          \
  }

__global__ __launch_bounds__(512) void k_attn(const bf16* __restrict__ HtB,
                                              const int* __restrict__ graph,
                                              const float* __restrict__ s1,
                                              const float* __restrict__ s2,
                                              float* __restrict__ out) {
  __shared__ __align__(16) bf16 Ps[2][AT_BM][LDP];  // 18,432 B (double buf)
  __shared__ float s2s[N_];                         // 8 KB
  __shared__ float sum_part[AT_BM][8];              // 2 KB
  __shared__ float row_sum[AT_BM];

  const int t = threadIdx.x;
  const int bid = blockIdx.x;
  const int b = bid & 7;  // XCD-affine: batch b -> XCD b
  const int i0 = (bid >> 3) * AT_BM;
  const int lane = t & 63, w = t >> 6;
  const int r31 = lane & 31, hf = lane >> 5;

  const bf16* Hb = HtB + (size_t)b * HTB_BATCH;
  const int* Gb = graph + ((size_t)b * N_ + i0) * N_;

  for (int c = t; c < N_; c += 512) s2s[c] = s2[b * N_ + c];

  const int pi = t >> 3;       // P row 0..63
  const int pj = (t & 7) * 8;  // P j-offset (8 values/thread)
  const float s1r = s1[b * N_ + i0 + pi];
  float rsum = 0.f;

  f32x16 acc[2][2];
#pragma unroll
  for (int i = 0; i < 2; ++i)
#pragma unroll
    for (int j = 0; j < 2; ++j)
#pragma unroll
      for (int r = 0; r < 16; ++r) acc[i][j][r] = 0.f;

  // prologue: B for it=0; graph for it=0 (ga) and it=1 (gb)
  bf16x8 bA[2][4], bB[2][4];
#pragma unroll
  for (int nt = 0; nt < 2; ++nt)
#pragma unroll
    for (int ks = 0; ks < 4; ++ks)
      bA[nt][ks] = *(const bf16x8*)&Hb[(size_t)(
          ((w * 2 + nt) * (N_ / 16) + ks) * 64 + lane) * 8];
  int4 ga0 = *(const int4*)&Gb[(size_t)pi * N_ + pj];
  int4 ga1 = *(const int4*)&Gb[(size_t)pi * N_ + pj + 4];
  int4 gb0 = *(const int4*)&Gb[(size_t)pi * N_ + AT_BK + pj];
  int4 gb1 = *(const int4*)&Gb[(size_t)pi * N_ + AT_BK + pj + 4];

  __syncthreads();  // s2s ready

#pragma unroll 1
  for (int i2 = 0; i2 < NIT / 2; ++i2) {
    const int it0 = i2 * 2;
    ATTN_BODY(0, bA, bB, ga0, ga1, it0);
    ATTN_BODY(1, bB, bA, gb0, gb1, it0 + 1);
  }

  // row sums
  sum_part[pi][t & 7] = rsum;
  __syncthreads();
  if (t < AT_BM) {
    float s = 0.f;
#pragma unroll
    for (int k = 0; k < 8; ++k) s += sum_part[t][k];
    row_sum[t] = s;
  }
  __syncthreads();

  // epilogue: normalize + elu + store
  // C/D layout (32x32): col = lane&31, row = (r&3) + 8*(r>>2) + 4*hf
#pragma unroll
  for (int mt = 0; mt < 2; ++mt) {
    float inv[16];
#pragma unroll
    for (int r = 0; r < 16; ++r)
      inv[r] = 1.f / row_sum[mt * 32 + (r & 3) + 8 * (r >> 2) + 4 * hf];
#pragma unroll
    for (int nt = 0; nt < 2; ++nt) {
      const int d = w * 64 + nt * 32 + r31;
#pragma unroll
      for (int r = 0; r < 16; ++r) {
        int i = mt * 32 + (r & 3) + 8 * (r >> 2) + 4 * hf;
        float x = acc[mt][nt][r] * inv[r];
        out[((size_t)b * N_ + i0 + i) * D_ + d] = (x > 0.f) ? x : expm1f(x);
      }
    }
  }
}

// ---------------------------------------------------------------------------
extern "C" void kernel_launch(void* const* d_in, const int* in_sizes, int n_in,
                              void* d_out, int out_size, void* d_ws,
                              size_t ws_size, hipStream_t stream) {
  const float* X = (const float*)d_in[0];
  const int* graph = (const int*)d_in[1];
  const float* W = (const float*)d_in[2];
  const float* a1 = (const float*)d_in[3];
  const float* a2 = (const float*)d_in[4];
  float* out = (float*)d_out;

  char* ws = (char*)d_ws;
  bf16* Wt = (bf16*)ws;                // 512 KB
  bf16* HtB = (bf16*)(ws + (1 << 19)); // 16 MB (frag-tiled layout)
  float* s1 = (float*)(ws + (1 << 19) + (16 << 20));
  float* s2 = s1 + NROWS;
  float* wa1 = s2 + NROWS;
  float* wa2 = wa1 + D_;

  hipLaunchKernelGGL(k_prep, dim3(512), dim3(256), 0, stream, W, Wt);
  hipLaunchKernelGGL(k_wa, dim3(128), dim3(256), 0, stream, W, a1, a2, wa1, wa2);
  hipLaunchKernelGGL(k_scores_x, dim3(NROWS / 4), dim3(256), 0, stream, X, wa1,
                     wa2, s1, s2);
  hipLaunchKernelGGL(k_hiddenT, dim3(NROWS / 128, D_ / 128), dim3(256), 0,
                     stream, X, Wt, HtB);
  hipLaunchKernelGGL(k_attn, dim3(N_ / AT_BM * B_), dim3(512), 0, stream, HtB,
                     graph, s1, s2, out);
}